// Round 1
// baseline (558.206 us; speedup 1.0000x reference)
//
#include <hip/hip_runtime.h>
#include <hip/hip_bf16.h>
#include <stdint.h>

// NTM single step. Sizes fixed by the problem.
#define B_   256
#define N_   32768
#define M_   64
#define R_   4
#define U_   256
#define DIN_ 512
#define DC_  768      // Din + R*M
#define J4_  1024     // 4*U
#define Q_   1024     // R*B  (query count for the attention part)

__device__ __forceinline__ float sigm(float x){ return 1.f/(1.f+__expf(-x)); }
__device__ __forceinline__ float tanh_f(float x){ float e=__expf(2.f*x); return 1.f - 2.f/(e+1.f); }
__device__ __forceinline__ unsigned short f2bf(float x){
    unsigned u = __float_as_uint(x);
    u += 0x7FFFu + ((u>>16)&1u);
    return (unsigned short)(u>>16);
}
__device__ __forceinline__ float bflo(unsigned u){ return __uint_as_float(u << 16); }
__device__ __forceinline__ float bfhi(unsigned u){ return __uint_as_float(u & 0xFFFF0000u); }

// ---------------- zero scratch that needs zeros ----------------
__global__ __launch_bounds__(256) void k_zero(int* lflag, float* l){
    int i = blockIdx.x*256 + threadIdx.x;
    if(i < N_) lflag[i] = 0;
    if(i < Q_) l[i] = 0.f;
}

// ---------------- row norms of A ----------------
__global__ __launch_bounds__(256) void k_anorm(const float* A, float* anorm){
    int n = blockIdx.x*4 + (threadIdx.x>>6);
    int lane = threadIdx.x & 63;
    float v = A[n*64 + lane];
    float s = v*v;
    #pragma unroll
    for(int m=1;m<64;m<<=1) s += __shfl_xor(s, m, 64);
    if(lane==0) anorm[n] = sqrtf(s);
}

// ---------------- per-row argmin of wu_prev ----------------
__global__ __launch_bounds__(256) void k_argmin(const float* wu, int* least, int* lflag){
    __shared__ float sv[256]; __shared__ int si[256];
    int b = blockIdx.x, t = threadIdx.x;
    const float* row = wu + (size_t)b*N_;
    float bv = 3.4e38f; int bi = 0;
    for(int n=t; n<N_; n+=256){ float v = row[n]; if(v < bv){ bv=v; bi=n; } }
    sv[t]=bv; si[t]=bi; __syncthreads();
    for(int s=128;s>0;s>>=1){
        if(t<s){
            float ov=sv[t+s]; int oi=si[t+s];
            if(ov<sv[t] || (ov==sv[t] && oi<si[t])){ sv[t]=ov; si[t]=oi; }
        }
        __syncthreads();
    }
    if(t==0){ least[b]=si[0]; lflag[si[0]]=1; }
}

// ---------------- LSTM gates GEMM (K split over 8 slices) ----------------
// gpart[ks][b][j] partial of gates = ctrl_in @ W + h @ Uw
__global__ __launch_bounds__(256) void k_lstm_gemm(const float* x, const float* rp, const float* h,
                                                   const float* W, const float* Uw, float* gpart){
    __shared__ float s_in[8*128];
    int bt = blockIdx.x >> 3, ks = blockIdx.x & 7;
    int b0 = bt*8, t = threadIdx.x;
    for(int i=t; i<1024; i+=256){
        int bb = i>>7, kk = i&127, k = ks*128 + kk, b = b0+bb;
        float v;
        if(k < DIN_) v = x[b*DIN_ + k];
        else if(k < DC_){ int k2 = k - DIN_; v = rp[(k2>>6)*(B_*M_) + b*M_ + (k2&63)]; }
        else v = h[b*U_ + (k-DC_)];
        s_in[bb*128 + kk] = v;
    }
    __syncthreads();
    float4 acc[8];
    #pragma unroll
    for(int i=0;i<8;i++) acc[i] = make_float4(0.f,0.f,0.f,0.f);
    const float* Wsel; int krel;
    if(ks < 6){ Wsel = W; krel = ks*128; } else { Wsel = Uw; krel = ks*128 - DC_; }
    int j0 = t*4;
    for(int kk=0; kk<128; kk++){
        float4 w = *(const float4*)(Wsel + (size_t)(krel+kk)*J4_ + j0);
        #pragma unroll
        for(int bb=0;bb<8;bb++){
            float s = s_in[bb*128 + kk];
            acc[bb].x += s*w.x; acc[bb].y += s*w.y; acc[bb].z += s*w.z; acc[bb].w += s*w.w;
        }
    }
    #pragma unroll
    for(int bb=0;bb<8;bb++)
        *(float4*)(gpart + (size_t)ks*(B_*J4_) + (size_t)(b0+bb)*J4_ + j0) = acc[bb];
}

// ---------------- LSTM activations -> h_new ----------------
__global__ __launch_bounds__(256) void k_lstm_act(const float* gpart, const float* bias, const float* c,
                                                  float* h_new, float* out){
    int b = blockIdx.x, u = threadIdx.x;
    float gi=bias[u], gf=bias[256+u], gg=bias[512+u], go=bias[768+u];
    #pragma unroll
    for(int s=0;s<8;s++){
        const float* gp = gpart + (size_t)s*(B_*J4_) + (size_t)b*J4_;
        gi += gp[u]; gf += gp[256+u]; gg += gp[512+u]; go += gp[768+u];
    }
    float cn = sigm(gf)*c[b*U_+u] + sigm(gi)*tanh_f(gg);
    float hn = sigm(go)*tanh_f(cn);
    h_new[b*U_+u] = hn;
    out[(size_t)b*512 + u] = hn;
}

// ---------------- keys kt, knorm, alpha, alpha-scaled kt ----------------
__global__ __launch_bounds__(64) void k_kta(const float* h_new, const float* Wk, const float* bk,
                                            const float* Wa, const float* ba,
                                            float* kt, float* aktw, float* alpha, float* knorm){
    __shared__ float h_l[256];
    int r = blockIdx.x >> 8, b = blockIdx.x & 255, m = threadIdx.x;
    for(int i=m;i<256;i+=64) h_l[i] = h_new[b*U_ + i];
    __syncthreads();
    float acc = bk[r*64 + m];
    const float* wkp = Wk + (size_t)r*U_*M_ + m;
    for(int u=0;u<256;u++) acc += h_l[u] * wkp[u*64];
    float k = tanh_f(acc);
    float s = k*k;
    #pragma unroll
    for(int mm=1;mm<64;mm<<=1) s += __shfl_xor(s, mm, 64);
    float pa = 0.f;
    #pragma unroll
    for(int uu=0; uu<4; uu++){ int u = m*4+uu; pa += h_l[u]*Wa[u*R_ + r]; }
    #pragma unroll
    for(int mm=1;mm<64;mm<<=1) pa += __shfl_xor(pa, mm, 64);
    float al = sigm(tanh_f(pa + ba[r]));
    int q = r*256 + b;
    kt[q*64 + m]   = k;
    aktw[q*64 + m] = al*k;
    if(m==0){ knorm[q] = sqrtf(s); alpha[q] = al; }
}

// ---------------- dense write-weight GEMM: G[r][n][m] = sum_b wr_prev[r][b][n]*aktw[r][b][m] ----------------
__global__ __launch_bounds__(256,2) void k_Ggemm(const float* wrp, const float* aktw, float* G){
    __shared__ float wr_l[32*256];
    __shared__ float akt_l[32*64];
    int r = blockIdx.x >> 7, nt = blockIdx.x & 127;
    int nb = nt*256, t = threadIdx.x;
    int tm = t & 15, tn = t >> 4;
    const float* wbase = wrp  + (size_t)r*((size_t)B_*N_);
    const float* abase = aktw + (size_t)r*(B_*M_);
    float4 acc[16];
    #pragma unroll
    for(int i=0;i<16;i++) acc[i]=make_float4(0.f,0.f,0.f,0.f);
    for(int tile=0; tile<8; tile++){
        int bb0 = tile*32;
        __syncthreads();
        for(int i=t; i<2048; i+=256){
            int kk = i>>6, cc = i&63;
            *(float4*)(wr_l + kk*256 + cc*4) = *(const float4*)(wbase + (size_t)(bb0+kk)*N_ + nb + cc*4);
        }
        for(int i=t; i<512; i+=256){
            int kk = i>>4, cc = i&15;
            *(float4*)(akt_l + kk*64 + cc*4) = *(const float4*)(abase + (bb0+kk)*64 + cc*4);
        }
        __syncthreads();
        #pragma unroll 4
        for(int kk=0; kk<32; kk++){
            float4 af = *(const float4*)(akt_l + kk*64 + tm*4);
            float4 w0 = *(const float4*)(wr_l + kk*256 + tn*16);
            float4 w1 = *(const float4*)(wr_l + kk*256 + tn*16 + 4);
            float4 w2 = *(const float4*)(wr_l + kk*256 + tn*16 + 8);
            float4 w3 = *(const float4*)(wr_l + kk*256 + tn*16 + 12);
#define GFMA(I, WV) { acc[I].x += (WV)*af.x; acc[I].y += (WV)*af.y; acc[I].z += (WV)*af.z; acc[I].w += (WV)*af.w; }
            GFMA(0,w0.x) GFMA(1,w0.y) GFMA(2,w0.z) GFMA(3,w0.w)
            GFMA(4,w1.x) GFMA(5,w1.y) GFMA(6,w1.z) GFMA(7,w1.w)
            GFMA(8,w2.x) GFMA(9,w2.y) GFMA(10,w2.z) GFMA(11,w2.w)
            GFMA(12,w3.x) GFMA(13,w3.y) GFMA(14,w3.z) GFMA(15,w3.w)
#undef GFMA
        }
    }
    float* gout = G + (size_t)r*((size_t)N_*64);
    #pragma unroll
    for(int i=0;i<16;i++)
        *(float4*)(gout + (size_t)(nb + tn*16 + i)*64 + tm*4) = acc[i];
}

// ---------------- one-hot (least-used) scatter into G ----------------
__global__ __launch_bounds__(64) void k_scatter(const float* kt, const float* alpha, const int* least, float* G){
    int r = blockIdx.x >> 8, b = blockIdx.x & 255, m = threadIdx.x;
    int q = r*256+b;
    float v = (1.f - alpha[q]) * kt[q*64 + m];
    int row = least[b];
    atomicAdd(G + (size_t)r*((size_t)N_*64) + (size_t)row*64 + m, v);
}

// ---------------- memory update: A_new = nested tanh chain ----------------
__global__ __launch_bounds__(256) void k_Aupd(const float* A, const float* G, const int* lflag, float* Anew){
    int i4 = blockIdx.x*256 + threadIdx.x;   // 524288 float4's
    int n = i4 >> 4;
    float er = lflag[n] ? 0.f : 1.f;
    float4 a = ((const float4*)A)[i4];
    float4 v = make_float4(a.x*er, a.y*er, a.z*er, a.w*er);
    #pragma unroll
    for(int r=0;r<4;r++){
        float4 g = ((const float4*)G)[(size_t)r*524288 + i4];
        v.x = tanh_f(v.x+g.x); v.y = tanh_f(v.y+g.y); v.z = tanh_f(v.z+g.z); v.w = tanh_f(v.w+g.w);
    }
    ((float4*)Anew)[i4] = v;
}

// ---------------- scores: P_t[n][q] = exp(cos(kt_q, A_n)) bf16, plus l[q] partials ----------------
__global__ __launch_bounds__(256,2) void k_scores(const float* kt, const float* A,
                                                  const float* knorm, const float* anorm,
                                                  unsigned short* Pt, float* l){
    __shared__ float4 kt_l[128*16];
    __shared__ float4 A_l[128*16];
    int nt = blockIdx.x >> 3, qt = blockIdx.x & 7;
    int nb = nt*128, qb = qt*128;
    int t = threadIdx.x, tq = t & 15, tn = t >> 4;
    for(int i=t;i<2048;i+=256){
        int row = i>>4, cc = i&15;
        kt_l[row*16 + (cc ^ (row>>3))] = *(const float4*)(kt + (qb+row)*64 + cc*4);
        A_l [row*16 + (cc ^ (row>>3))] = *(const float4*)(A + (size_t)(nb+row)*64 + cc*4);
    }
    __syncthreads();
    float acc[64];
    #pragma unroll
    for(int i=0;i<64;i++) acc[i]=0.f;
    #pragma unroll
    for(int mq=0; mq<16; mq++){
        float4 kf[8], af[8];
        #pragma unroll
        for(int i=0;i<8;i++) kf[i] = kt_l[(tq*8+i)*16 + (mq ^ tq)];
        #pragma unroll
        for(int j=0;j<8;j++) af[j] = A_l[(tn*8+j)*16 + (mq ^ tn)];
        #pragma unroll
        for(int i=0;i<8;i++)
        #pragma unroll
        for(int j=0;j<8;j++)
            acc[i*8+j] += kf[i].x*af[j].x + kf[i].y*af[j].y + kf[i].z*af[j].z + kf[i].w*af[j].w;
    }
    float kn[8], an[8];
    #pragma unroll
    for(int i=0;i<8;i++) kn[i] = knorm[qb + tq*8 + i];
    #pragma unroll
    for(int j=0;j<8;j++) an[j] = anorm[nb + tn*8 + j];
    float lp[8];
    #pragma unroll
    for(int i=0;i<8;i++) lp[i]=0.f;
    #pragma unroll
    for(int j=0;j<8;j++){
        unsigned pk[4];
        #pragma unroll
        for(int i2=0;i2<4;i2++){
            float p0 = __expf(__fdividef(acc[(i2*2  )*8+j], kn[i2*2  ]*an[j] + 1e-16f));
            float p1 = __expf(__fdividef(acc[(i2*2+1)*8+j], kn[i2*2+1]*an[j] + 1e-16f));
            lp[i2*2] += p0; lp[i2*2+1] += p1;
            pk[i2] = (unsigned)f2bf(p0) | ((unsigned)f2bf(p1)<<16);
        }
        *(uint4*)(Pt + (size_t)(nb + tn*8 + j)*Q_ + qb + tq*8) = make_uint4(pk[0],pk[1],pk[2],pk[3]);
    }
    __syncthreads();
    float* lred = (float*)A_l;
    #pragma unroll
    for(int i=0;i<8;i++) lred[tn*128 + tq*8 + i] = lp[i];
    __syncthreads();
    if(t < 128){
        float s = 0.f;
        #pragma unroll
        for(int g=0; g<16; g++) s += lred[g*128 + t];
        atomicAdd(l + qb + t, s);
    }
}

// ---------------- PV: part[ch][q][m] = sum_{n in chunk} P[n][q]*Anew[n][m] ----------------
__global__ __launch_bounds__(256,4) void k_pv(const unsigned short* Pt, const float* Anew, float* part){
    __shared__ uint4  P_l[32*16];
    __shared__ float4 V_l[32*16];
    int ch = blockIdx.x >> 3, qt = blockIdx.x & 7;
    int qb = qt*128, n0c = ch*512;
    int t = threadIdx.x, tq = t & 15, tm = t >> 4;
    float4 acc[8];
    #pragma unroll
    for(int i=0;i<8;i++) acc[i]=make_float4(0.f,0.f,0.f,0.f);
    for(int tile=0; tile<16; tile++){
        int n0 = n0c + tile*32;
        __syncthreads();
        for(int i=t;i<512;i+=256){
            int row = i>>4, cc = i&15;
            P_l[row*16 + cc] = *(const uint4*)(Pt + (size_t)(n0+row)*Q_ + qb + cc*8);
            V_l[row*16 + cc] = *(const float4*)(Anew + (size_t)(n0+row)*64 + cc*4);
        }
        __syncthreads();
        #pragma unroll 4
        for(int kk=0;kk<32;kk++){
            uint4 pw = P_l[kk*16 + tq];
            float4 vf = V_l[kk*16 + tm];
            float p0=bflo(pw.x), p1=bfhi(pw.x), p2=bflo(pw.y), p3=bfhi(pw.y);
            float p4=bflo(pw.z), p5=bfhi(pw.z), p6=bflo(pw.w), p7=bfhi(pw.w);
#define PVF(I, PV) { acc[I].x += (PV)*vf.x; acc[I].y += (PV)*vf.y; acc[I].z += (PV)*vf.z; acc[I].w += (PV)*vf.w; }
            PVF(0,p0) PVF(1,p1) PVF(2,p2) PVF(3,p3) PVF(4,p4) PVF(5,p5) PVF(6,p6) PVF(7,p7)
#undef PVF
        }
    }
    #pragma unroll
    for(int i=0;i<8;i++)
        *(float4*)(part + (size_t)ch*(Q_*64) + (size_t)(qb + tq*8 + i)*64 + tm*4) = acc[i];
}

// ---------------- final reduce over chunks, normalize, write reads ----------------
__global__ __launch_bounds__(256) void k_reduce(const float* part, const float* l, float* out){
    int tg = blockIdx.x*256 + threadIdx.x;   // 65536 = Q_*64
    int q = tg >> 6, m = tg & 63;
    float s = 0.f;
    for(int cc=0;cc<64;cc++) s += part[(size_t)cc*(Q_*64) + tg];
    float val = s / l[q];
    int r = q >> 8, b = q & 255;
    out[(size_t)b*512 + 256 + r*64 + m] = val;
}

extern "C" void kernel_launch(void* const* d_in, const int* in_sizes, int n_in,
                              void* d_out, int out_size, void* d_ws, size_t ws_size,
                              hipStream_t stream) {
    const float* x        = (const float*)d_in[0];
    const float* A        = (const float*)d_in[1];
    const float* wr_prev  = (const float*)d_in[2];
    const float* wu_prev  = (const float*)d_in[3];
    const float* read_prev= (const float*)d_in[4];
    const float* h        = (const float*)d_in[5];
    const float* c        = (const float*)d_in[6];
    const float* W        = (const float*)d_in[7];
    const float* Uw       = (const float*)d_in[8];
    const float* bvec     = (const float*)d_in[9];
    const float* Wk       = (const float*)d_in[10];
    const float* bk       = (const float*)d_in[11];
    const float* Wa       = (const float*)d_in[12];
    const float* ba       = (const float*)d_in[13];
    float* out = (float*)d_out;

    char* wsp = (char*)d_ws;
    float* G      = (float*)(wsp);                      // 33,554,432 B (also gpart 8MB, pv-part 16.8MB reuse)
    float* Anew   = (float*)(wsp + 33554432);           // 8,388,608
    unsigned short* Pt = (unsigned short*)(wsp + 41943040); // 67,108,864
    float* h_new  = (float*)(wsp + 109051904);
    float* kt     = (float*)(wsp + 109314048);
    float* aktw   = (float*)(wsp + 109576192);
    float* alpha  = (float*)(wsp + 109838336);
    float* knorm  = (float*)(wsp + 109842432);
    float* anorm  = (float*)(wsp + 109846528);
    int*   lflag  = (int*)  (wsp + 109977600);
    float* l      = (float*)(wsp + 110108672);
    int*   least  = (int*)  (wsp + 110112768);

    k_zero     <<<128, 256, 0, stream>>>(lflag, l);
    k_anorm    <<<8192,256, 0, stream>>>(A, anorm);
    k_argmin   <<<256, 256, 0, stream>>>(wu_prev, least, lflag);
    k_lstm_gemm<<<256, 256, 0, stream>>>(x, read_prev, h, W, Uw, G);
    k_lstm_act <<<256, 256, 0, stream>>>(G, bvec, c, h_new, out);
    k_kta      <<<1024, 64, 0, stream>>>(h_new, Wk, bk, Wa, ba, kt, aktw, alpha, knorm);
    k_Ggemm    <<<512, 256, 0, stream>>>(wr_prev, aktw, G);
    k_scatter  <<<1024, 64, 0, stream>>>(kt, alpha, least, G);
    k_Aupd     <<<2048,256, 0, stream>>>(A, G, lflag, Anew);
    k_scores   <<<2048,256, 0, stream>>>(kt, A, knorm, anorm, Pt, l);
    k_pv       <<<512, 256, 0, stream>>>(Pt, Anew, G);
    k_reduce   <<<256, 256, 0, stream>>>(G, l, out);
}

// Round 2
// 494.931 us; speedup vs baseline: 1.1278x; 1.1278x over previous
//
#include <hip/hip_runtime.h>
#include <hip/hip_bf16.h>
#include <stdint.h>

// NTM single step. Sizes fixed by the problem.
#define B_   256
#define N_   32768
#define M_   64
#define R_   4
#define U_   256
#define DIN_ 512
#define DC_  768      // Din + R*M
#define J4_  1024     // 4*U
#define Q_   1024     // R*B  (query count for the attention part)
#define NPART_ 32     // n-chunks for fused attention partials

typedef __attribute__((ext_vector_type(8))) short short8v;   // 8 bf16 (4 VGPRs)
typedef __attribute__((ext_vector_type(4))) float f32x4;

__device__ __forceinline__ float sigm(float x){ return 1.f/(1.f+__expf(-x)); }
__device__ __forceinline__ float tanh_f(float x){ float e=__expf(2.f*x); return 1.f - 2.f/(e+1.f); }
__device__ __forceinline__ unsigned short f2bf(float x){
    unsigned u = __float_as_uint(x);
    u += 0x7FFFu + ((u>>16)&1u);
    return (unsigned short)(u>>16);
}

// ---------------- zero scratch that needs zeros ----------------
__global__ __launch_bounds__(256) void k_zero(int* lflag, float* l){
    int i = blockIdx.x*256 + threadIdx.x;
    if(i < N_) lflag[i] = 0;
    if(i < Q_) l[i] = 0.f;
}

// ---------------- row norms of A + bf16 copy of A ----------------
__global__ __launch_bounds__(256) void k_anorm(const float* A, float* anorm, unsigned short* A_bf){
    int n = blockIdx.x*4 + (threadIdx.x>>6);
    int lane = threadIdx.x & 63;
    float v = A[n*64 + lane];
    A_bf[n*64 + lane] = f2bf(v);
    float s = v*v;
    #pragma unroll
    for(int m=1;m<64;m<<=1) s += __shfl_xor(s, m, 64);
    if(lane==0) anorm[n] = sqrtf(s);
}

// ---------------- per-row argmin of wu_prev ----------------
__global__ __launch_bounds__(256) void k_argmin(const float* wu, int* least, int* lflag){
    __shared__ float sv[256]; __shared__ int si[256];
    int b = blockIdx.x, t = threadIdx.x;
    const float* row = wu + (size_t)b*N_;
    float bv = 3.4e38f; int bi = 0;
    for(int n=t; n<N_; n+=256){ float v = row[n]; if(v < bv){ bv=v; bi=n; } }
    sv[t]=bv; si[t]=bi; __syncthreads();
    for(int s=128;s>0;s>>=1){
        if(t<s){
            float ov=sv[t+s]; int oi=si[t+s];
            if(ov<sv[t] || (ov==sv[t] && oi<si[t])){ sv[t]=ov; si[t]=oi; }
        }
        __syncthreads();
    }
    if(t==0){ least[b]=si[0]; lflag[si[0]]=1; }
}

// ---------------- LSTM gates GEMM (K split over 8 slices) ----------------
__global__ __launch_bounds__(256) void k_lstm_gemm(const float* x, const float* rp, const float* h,
                                                   const float* W, const float* Uw, float* gpart){
    __shared__ float s_in[8*128];
    int bt = blockIdx.x >> 3, ks = blockIdx.x & 7;
    int b0 = bt*8, t = threadIdx.x;
    for(int i=t; i<1024; i+=256){
        int bb = i>>7, kk = i&127, k = ks*128 + kk, b = b0+bb;
        float v;
        if(k < DIN_) v = x[b*DIN_ + k];
        else if(k < DC_){ int k2 = k - DIN_; v = rp[(k2>>6)*(B_*M_) + b*M_ + (k2&63)]; }
        else v = h[b*U_ + (k-DC_)];
        s_in[bb*128 + kk] = v;
    }
    __syncthreads();
    float4 acc[8];
    #pragma unroll
    for(int i=0;i<8;i++) acc[i] = make_float4(0.f,0.f,0.f,0.f);
    const float* Wsel; int krel;
    if(ks < 6){ Wsel = W; krel = ks*128; } else { Wsel = Uw; krel = ks*128 - DC_; }
    int j0 = t*4;
    for(int kk=0; kk<128; kk++){
        float4 w = *(const float4*)(Wsel + (size_t)(krel+kk)*J4_ + j0);
        #pragma unroll
        for(int bb=0;bb<8;bb++){
            float s = s_in[bb*128 + kk];
            acc[bb].x += s*w.x; acc[bb].y += s*w.y; acc[bb].z += s*w.z; acc[bb].w += s*w.w;
        }
    }
    #pragma unroll
    for(int bb=0;bb<8;bb++)
        *(float4*)(gpart + (size_t)ks*(B_*J4_) + (size_t)(b0+bb)*J4_ + j0) = acc[bb];
}

// ---------------- LSTM activations -> h_new ----------------
__global__ __launch_bounds__(256) void k_lstm_act(const float* gpart, const float* bias, const float* c,
                                                  float* h_new, float* out){
    int b = blockIdx.x, u = threadIdx.x;
    float gi=bias[u], gf=bias[256+u], gg=bias[512+u], go=bias[768+u];
    #pragma unroll
    for(int s=0;s<8;s++){
        const float* gp = gpart + (size_t)s*(B_*J4_) + (size_t)b*J4_;
        gi += gp[u]; gf += gp[256+u]; gg += gp[512+u]; go += gp[768+u];
    }
    float cn = sigm(gf)*c[b*U_+u] + sigm(gi)*tanh_f(gg);
    float hn = sigm(go)*tanh_f(cn);
    h_new[b*U_+u] = hn;
    out[(size_t)b*512 + u] = hn;
}

// ---------------- keys kt (+bf16), knorm, alpha, alpha-scaled kt ----------------
__global__ __launch_bounds__(64) void k_kta(const float* h_new, const float* Wk, const float* bk,
                                            const float* Wa, const float* ba,
                                            float* kt, unsigned short* kt_bf, float* aktw,
                                            float* alpha, float* knorm){
    __shared__ float h_l[256];
    int r = blockIdx.x >> 8, b = blockIdx.x & 255, m = threadIdx.x;
    for(int i=m;i<256;i+=64) h_l[i] = h_new[b*U_ + i];
    __syncthreads();
    float acc = bk[r*64 + m];
    const float* wkp = Wk + (size_t)r*U_*M_ + m;
    for(int u=0;u<256;u++) acc += h_l[u] * wkp[u*64];
    float k = tanh_f(acc);
    float s = k*k;
    #pragma unroll
    for(int mm=1;mm<64;mm<<=1) s += __shfl_xor(s, mm, 64);
    float pa = 0.f;
    #pragma unroll
    for(int uu=0; uu<4; uu++){ int u = m*4+uu; pa += h_l[u]*Wa[u*R_ + r]; }
    #pragma unroll
    for(int mm=1;mm<64;mm<<=1) pa += __shfl_xor(pa, mm, 64);
    float al = sigm(tanh_f(pa + ba[r]));
    int q = r*256 + b;
    kt[q*64 + m]    = k;
    kt_bf[q*64 + m] = f2bf(k);
    aktw[q*64 + m]  = al*k;
    if(m==0){ knorm[q] = sqrtf(s); alpha[q] = al; }
}

// ---------------- dense write-weight GEMM: G[r][n][m] = sum_b wr_prev[r][b][n]*aktw[r][b][m] ----------------
__global__ __launch_bounds__(256,2) void k_Ggemm(const float* wrp, const float* aktw, float* G){
    __shared__ float wr_l[32*256];
    __shared__ float akt_l[32*64];
    int r = blockIdx.x >> 7, nt = blockIdx.x & 127;
    int nb = nt*256, t = threadIdx.x;
    int tm = t & 15, tn = t >> 4;
    const float* wbase = wrp  + (size_t)r*((size_t)B_*N_);
    const float* abase = aktw + (size_t)r*(B_*M_);
    float4 acc[16];
    #pragma unroll
    for(int i=0;i<16;i++) acc[i]=make_float4(0.f,0.f,0.f,0.f);
    for(int tile=0; tile<8; tile++){
        int bb0 = tile*32;
        __syncthreads();
        for(int i=t; i<2048; i+=256){
            int kk = i>>6, cc = i&63;
            *(float4*)(wr_l + kk*256 + cc*4) = *(const float4*)(wbase + (size_t)(bb0+kk)*N_ + nb + cc*4);
        }
        for(int i=t; i<512; i+=256){
            int kk = i>>4, cc = i&15;
            *(float4*)(akt_l + kk*64 + cc*4) = *(const float4*)(abase + (bb0+kk)*64 + cc*4);
        }
        __syncthreads();
        #pragma unroll 4
        for(int kk=0; kk<32; kk++){
            float4 af = *(const float4*)(akt_l + kk*64 + tm*4);
            float4 w0 = *(const float4*)(wr_l + kk*256 + tn*16);
            float4 w1 = *(const float4*)(wr_l + kk*256 + tn*16 + 4);
            float4 w2 = *(const float4*)(wr_l + kk*256 + tn*16 + 8);
            float4 w3 = *(const float4*)(wr_l + kk*256 + tn*16 + 12);
#define GFMA(I, WV) { acc[I].x += (WV)*af.x; acc[I].y += (WV)*af.y; acc[I].z += (WV)*af.z; acc[I].w += (WV)*af.w; }
            GFMA(0,w0.x) GFMA(1,w0.y) GFMA(2,w0.z) GFMA(3,w0.w)
            GFMA(4,w1.x) GFMA(5,w1.y) GFMA(6,w1.z) GFMA(7,w1.w)
            GFMA(8,w2.x) GFMA(9,w2.y) GFMA(10,w2.z) GFMA(11,w2.w)
            GFMA(12,w3.x) GFMA(13,w3.y) GFMA(14,w3.z) GFMA(15,w3.w)
#undef GFMA
        }
    }
    float* gout = G + (size_t)r*((size_t)N_*64);
    #pragma unroll
    for(int i=0;i<16;i++)
        *(float4*)(gout + (size_t)(nb + tn*16 + i)*64 + tm*4) = acc[i];
}

// ---------------- one-hot (least-used) scatter into G ----------------
__global__ __launch_bounds__(64) void k_scatter(const float* kt, const float* alpha, const int* least, float* G){
    int r = blockIdx.x >> 8, b = blockIdx.x & 255, m = threadIdx.x;
    int q = r*256+b;
    float v = (1.f - alpha[q]) * kt[q*64 + m];
    int row = least[b];
    atomicAdd(G + (size_t)r*((size_t)N_*64) + (size_t)row*64 + m, v);
}

// ---------------- memory update: A_new = nested tanh chain ----------------
__global__ __launch_bounds__(256) void k_Aupd(const float* A, const float* G, const int* lflag, float* Anew){
    int i4 = blockIdx.x*256 + threadIdx.x;   // 524288 float4's
    int n = i4 >> 4;
    float er = lflag[n] ? 0.f : 1.f;
    float4 a = ((const float4*)A)[i4];
    float4 v = make_float4(a.x*er, a.y*er, a.z*er, a.w*er);
    #pragma unroll
    for(int r=0;r<4;r++){
        float4 g = ((const float4*)G)[(size_t)r*524288 + i4];
        v.x = tanh_f(v.x+g.x); v.y = tanh_f(v.y+g.y); v.z = tanh_f(v.z+g.z); v.w = tanh_f(v.w+g.w);
    }
    ((float4*)Anew)[i4] = v;
}

// ---------------- transpose Anew -> Vt_bf[m][n] (bf16) ----------------
__global__ __launch_bounds__(256) void k_vt(const float* Anew, unsigned short* Vt){
    __shared__ __align__(16) unsigned short lt[4096];   // [64 m][64 n]
    int n0 = blockIdx.x*64, t = threadIdx.x;
    int row = t>>2, cb = t&3;
    #pragma unroll
    for(int i=0;i<4;i++){
        int cidx = cb*4 + i;                   // 16 float4 per row
        float4 f = *(const float4*)(Anew + (size_t)(n0+row)*64 + cidx*4);
        int m0 = cidx*4;
        lt[(m0  )*64 + row] = f2bf(f.x);
        lt[(m0+1)*64 + row] = f2bf(f.y);
        lt[(m0+2)*64 + row] = f2bf(f.z);
        lt[(m0+3)*64 + row] = f2bf(f.w);
    }
    __syncthreads();
    int mr = t>>2;
    #pragma unroll
    for(int cc=0; cc<2; cc++){
        int c = (t&3) + cc*4;                  // 8 chunks of 16B per m-row
        uint4 v = *(const uint4*)(lt + mr*64 + c*8);
        *(uint4*)(Vt + (size_t)mr*N_ + n0 + c*8) = v;
    }
}

// ---------------- fused attention: scores (MFMA) -> LDS P (bf16) -> PV (MFMA) ----------------
// grid: 512 blocks = 32 n-parts x 16 q-tiles; block 256 = 4 waves, wave w owns 16 q rows.
__global__ __launch_bounds__(256) void k_attn(const unsigned short* kt_bf, const unsigned short* A_bf,
                                              const unsigned short* Vt, const float* knorm,
                                              const float* anorm, float* part, float* l){
    __shared__ __align__(16) unsigned short Pl[64*256];   // [64 q][256 n], XOR-swizzled
    int nc = blockIdx.x >> 4, qt = blockIdx.x & 15;
    int qb = qt*64, nb = nc*1024;
    int lane = threadIdx.x & 63, w = threadIdx.x >> 6;
    int r16 = lane & 15, hq = lane >> 4;
    // kt A-fragments (wave-resident)
    const short8v* kp = (const short8v*)(kt_bf + (size_t)(qb + w*16 + r16)*64 + hq*8);
    short8v ka0 = kp[0], ka1 = kp[4];
    float kn[4];
    #pragma unroll
    for(int j=0;j<4;j++) kn[j] = knorm[qb + w*16 + hq*4 + j];
    f32x4 O[4];
    #pragma unroll
    for(int mt=0;mt<4;mt++) O[mt] = (f32x4){0.f,0.f,0.f,0.f};
    float lp[4] = {0.f,0.f,0.f,0.f};
    int g2 = (r16 >> 2) & 3;

    for(int c=0; c<4; c++){
        int n0c = nb + c*256;
        __syncthreads();   // protect LDS from previous chunk's readers
        // ---- scores phase: P[64q][256n] ----
        for(int nt=0; nt<16; nt++){
            int ntb = n0c + nt*16;
            const short8v* bp = (const short8v*)(A_bf + (size_t)(ntb + r16)*64 + hq*8);
            f32x4 acc = (f32x4){0.f,0.f,0.f,0.f};
            acc = __builtin_amdgcn_mfma_f32_16x16x32_bf16(ka0, bp[0], acc, 0, 0, 0);
            acc = __builtin_amdgcn_mfma_f32_16x16x32_bf16(ka1, bp[4], acc, 0, 0, 0);
            float an = anorm[ntb + r16];
            unsigned um[4];
            #pragma unroll
            for(int j=0;j<4;j++){
                float p = __expf(__fdividef(acc[j], kn[j]*an + 1e-16f));
                lp[j] += p;
                um[j] = (unsigned)f2bf(p);
            }
            int nl = nt*16 + (r16 & ~1);
            #pragma unroll
            for(int j=0;j<4;j++){
                unsigned up = __shfl_xor((int)um[j], 1, 64);
                if((lane & 1) == 0){
                    unsigned word = um[j] | (up << 16);
                    int byteoff = (w*16 + hq*4 + j)*512 + ((nl ^ (hq<<4)) << 1);
                    *(unsigned*)((char*)Pl + byteoff) = word;
                }
            }
        }
        __syncthreads();
        // ---- PV phase: O += P(16q x 32n) * Vt(32n x 16m) ----
        #pragma unroll 2
        for(int ks=0; ks<8; ks++){
            short8v pa = *(const short8v*)((const char*)Pl +
                          ((w*16 + r16)*512 + (((ks*32 + hq*8) ^ (g2<<4)) << 1)));
            #pragma unroll
            for(int mt=0; mt<4; mt++){
                const short8v* vp = (const short8v*)(Vt + (size_t)(mt*16 + r16)*N_ + n0c + ks*32 + hq*8);
                O[mt] = __builtin_amdgcn_mfma_f32_16x16x32_bf16(pa, vp[0], O[mt], 0, 0, 0);
            }
        }
    }
    // ---- store O partials ----
    #pragma unroll
    for(int mt=0; mt<4; mt++)
        #pragma unroll
        for(int j=0;j<4;j++)
            part[((size_t)nc*Q_ + (qb + w*16 + hq*4 + j))*64 + mt*16 + r16] = O[mt][j];
    // ---- l partials: reduce over the 16 lanes of each hq-group, one atomic per q ----
    #pragma unroll
    for(int j=0;j<4;j++){
        #pragma unroll
        for(int m2=1;m2<16;m2<<=1) lp[j] += __shfl_xor(lp[j], m2, 64);
        if(r16 == 0) atomicAdd(l + qb + w*16 + hq*4 + j, lp[j]);
    }
}

// ---------------- final reduce over n-parts, normalize, write reads ----------------
__global__ __launch_bounds__(256) void k_reduce(const float* part, const float* l, float* out){
    int tg = blockIdx.x*256 + threadIdx.x;   // 65536 = Q_*64
    int q = tg >> 6, m = tg & 63;
    float s = 0.f;
    for(int cc=0;cc<NPART_;cc++) s += part[(size_t)cc*(Q_*64) + tg];
    float val = s / l[q];
    int r = q >> 8, b = q & 255;
    out[(size_t)b*512 + 256 + r*64 + m] = val;
}

extern "C" void kernel_launch(void* const* d_in, const int* in_sizes, int n_in,
                              void* d_out, int out_size, void* d_ws, size_t ws_size,
                              hipStream_t stream) {
    const float* x        = (const float*)d_in[0];
    const float* A        = (const float*)d_in[1];
    const float* wr_prev  = (const float*)d_in[2];
    const float* wu_prev  = (const float*)d_in[3];
    const float* read_prev= (const float*)d_in[4];
    const float* h        = (const float*)d_in[5];
    const float* c        = (const float*)d_in[6];
    const float* W        = (const float*)d_in[7];
    const float* Uw       = (const float*)d_in[8];
    const float* bvec     = (const float*)d_in[9];
    const float* Wk       = (const float*)d_in[10];
    const float* bk       = (const float*)d_in[11];
    const float* Wa       = (const float*)d_in[12];
    const float* ba       = (const float*)d_in[13];
    float* out = (float*)d_out;

    char* wsp = (char*)d_ws;
    float* G      = (float*)(wsp);                        // 32 MB (also lstm gpart 8MB reuse)
    float* Anew   = (float*)(wsp + 33554432);             // 8 MB
    float* part   = (float*)(wsp + 41943040);             // 8 MB (attn O partials)
    unsigned short* A_bf  = (unsigned short*)(wsp + 50331648);  // 4 MB
    unsigned short* Vt_bf = (unsigned short*)(wsp + 54525952);  // 4 MB
    unsigned short* kt_bf = (unsigned short*)(wsp + 58720256);  // 128 KB
    float* h_new  = (float*)(wsp + 58851328);
    float* kt     = (float*)(wsp + 59113472);
    float* aktw   = (float*)(wsp + 59375616);
    float* alpha  = (float*)(wsp + 59637760);
    float* knorm  = (float*)(wsp + 59641856);
    float* anorm  = (float*)(wsp + 59645952);
    int*   lflag  = (int*)  (wsp + 59777024);
    float* l      = (float*)(wsp + 59908096);
    int*   least  = (int*)  (wsp + 59912192);

    k_zero     <<<128, 256, 0, stream>>>(lflag, l);
    k_anorm    <<<8192,256, 0, stream>>>(A, anorm, A_bf);
    k_argmin   <<<256, 256, 0, stream>>>(wu_prev, least, lflag);
    k_lstm_gemm<<<256, 256, 0, stream>>>(x, read_prev, h, W, Uw, G);
    k_lstm_act <<<256, 256, 0, stream>>>(G, bvec, c, h_new, out);
    k_kta      <<<1024, 64, 0, stream>>>(h_new, Wk, bk, Wa, ba, kt, kt_bf, aktw, alpha, knorm);
    k_Ggemm    <<<512, 256, 0, stream>>>(wr_prev, aktw, G);
    k_scatter  <<<1024, 64, 0, stream>>>(kt, alpha, least, G);
    k_Aupd     <<<2048,256, 0, stream>>>(A, G, lflag, Anew);
    k_vt       <<<512, 256, 0, stream>>>(Anew, Vt_bf);
    k_attn     <<<512, 256, 0, stream>>>(kt_bf, A_bf, Vt_bf, knorm, anorm, part, l);
    k_reduce   <<<256, 256, 0, stream>>>(part, l, out);
}

// Round 3
// 453.289 us; speedup vs baseline: 1.2315x; 1.0919x over previous
//
#include <hip/hip_runtime.h>
#include <hip/hip_bf16.h>
#include <stdint.h>

// NTM single step. Sizes fixed by the problem.
#define B_   256
#define N_   32768
#define M_   64
#define R_   4
#define U_   256
#define DIN_ 512
#define DC_  768      // Din + R*M
#define J4_  1024     // 4*U
#define Q_   1024     // R*B
#define NPART_ 64     // n-chunks for fused attention partials

typedef __attribute__((ext_vector_type(8))) short short8v;   // 8 bf16 (4 VGPRs)
typedef __attribute__((ext_vector_type(4))) float f32x4;

__device__ __forceinline__ float sigm(float x){ return 1.f/(1.f+__expf(-x)); }
__device__ __forceinline__ float tanh_f(float x){ float e=__expf(2.f*x); return 1.f - 2.f/(e+1.f); }
__device__ __forceinline__ unsigned short f2bf(float x){
    unsigned u = __float_as_uint(x);
    u += 0x7FFFu + ((u>>16)&1u);
    return (unsigned short)(u>>16);
}

// ---------------- zero scratch that needs zeros ----------------
__global__ __launch_bounds__(256) void k_zero(int* lflag, float* l){
    int i = blockIdx.x*256 + threadIdx.x;
    if(i < N_) lflag[i] = 0;
    if(i < Q_) l[i] = 0.f;
}

// ---------------- row norms of A + bf16 copy of A ----------------
__global__ __launch_bounds__(256) void k_anorm(const float* A, float* anorm, unsigned short* A_bf){
    int n = blockIdx.x*4 + (threadIdx.x>>6);
    int lane = threadIdx.x & 63;
    float v = A[n*64 + lane];
    A_bf[n*64 + lane] = f2bf(v);
    float s = v*v;
    #pragma unroll
    for(int m=1;m<64;m<<=1) s += __shfl_xor(s, m, 64);
    if(lane==0) anorm[n] = sqrtf(s);
}

// ---------------- per-row argmin of wu_prev ----------------
__global__ __launch_bounds__(256) void k_argmin(const float* wu, int* least, int* lflag){
    __shared__ float sv[256]; __shared__ int si[256];
    int b = blockIdx.x, t = threadIdx.x;
    const float* row = wu + (size_t)b*N_;
    float bv = 3.4e38f; int bi = 0;
    for(int n=t; n<N_; n+=256){ float v = row[n]; if(v < bv){ bv=v; bi=n; } }
    sv[t]=bv; si[t]=bi; __syncthreads();
    for(int s=128;s>0;s>>=1){
        if(t<s){
            float ov=sv[t+s]; int oi=si[t+s];
            if(ov<sv[t] || (ov==sv[t] && oi<si[t])){ sv[t]=ov; si[t]=oi; }
        }
        __syncthreads();
    }
    if(t==0){ least[b]=si[0]; lflag[si[0]]=1; }
}

// ---------------- LSTM gates GEMM (16 K-slices of 64) ----------------
__global__ __launch_bounds__(256) void k_lstm_gemm(const float* x, const float* rp, const float* h,
                                                   const float* W, const float* Uw, float* gpart){
    __shared__ float s_in[8*64];
    int bt = blockIdx.x >> 4, ks = blockIdx.x & 15;
    int b0 = bt*8, t = threadIdx.x;
    #pragma unroll
    for(int i=t; i<512; i+=256){
        int bb = i>>6, kk = i&63, b = b0+bb;
        float v;
        if(ks < 8)       v = x[b*DIN_ + ks*64 + kk];
        else if(ks < 12) v = rp[(size_t)(ks-8)*(B_*M_) + b*64 + kk];
        else             v = h[b*U_ + (ks-12)*64 + kk];
        s_in[bb*64 + kk] = v;
    }
    __syncthreads();
    float4 acc[8];
    #pragma unroll
    for(int i=0;i<8;i++) acc[i] = make_float4(0.f,0.f,0.f,0.f);
    const float* Wsel; int krel;
    if(ks < 12){ Wsel = W; krel = ks*64; } else { Wsel = Uw; krel = (ks-12)*64; }
    int j0 = t*4;
    #pragma unroll 4
    for(int kk=0; kk<64; kk++){
        float4 w = *(const float4*)(Wsel + (size_t)(krel+kk)*J4_ + j0);
        #pragma unroll
        for(int bb=0;bb<8;bb++){
            float s = s_in[bb*64 + kk];
            acc[bb].x += s*w.x; acc[bb].y += s*w.y; acc[bb].z += s*w.z; acc[bb].w += s*w.w;
        }
    }
    #pragma unroll
    for(int bb=0;bb<8;bb++)
        *(float4*)(gpart + (size_t)ks*(B_*J4_) + (size_t)(b0+bb)*J4_ + j0) = acc[bb];
}

// ---------------- LSTM activations -> h_new ----------------
__global__ __launch_bounds__(256) void k_lstm_act(const float* gpart, const float* bias, const float* c,
                                                  float* h_new, float* out){
    int b = blockIdx.x, u = threadIdx.x;
    float gi=bias[u], gf=bias[256+u], gg=bias[512+u], go=bias[768+u];
    #pragma unroll
    for(int s=0;s<16;s++){
        const float* gp = gpart + (size_t)s*(B_*J4_) + (size_t)b*J4_;
        gi += gp[u]; gf += gp[256+u]; gg += gp[512+u]; go += gp[768+u];
    }
    float cn = sigm(gf)*c[b*U_+u] + sigm(gi)*tanh_f(gg);
    float hn = sigm(go)*tanh_f(cn);
    h_new[b*U_+u] = hn;
    out[(size_t)b*512 + u] = hn;
}

// ---------------- keys kt (+bf16), knorm, alpha, aktT[r][m][b] bf16 ----------------
__global__ __launch_bounds__(64) void k_kta(const float* h_new, const float* Wk, const float* bk,
                                            const float* Wa, const float* ba,
                                            float* kt, unsigned short* kt_bf, unsigned short* aktT,
                                            float* alpha, float* knorm){
    __shared__ float h_l[256];
    int r = blockIdx.x >> 8, b = blockIdx.x & 255, m = threadIdx.x;
    for(int i=m;i<256;i+=64) h_l[i] = h_new[b*U_ + i];
    __syncthreads();
    float acc = bk[r*64 + m];
    const float* wkp = Wk + (size_t)r*U_*M_ + m;
    for(int u=0;u<256;u++) acc += h_l[u] * wkp[u*64];
    float k = tanh_f(acc);
    float s = k*k;
    #pragma unroll
    for(int mm=1;mm<64;mm<<=1) s += __shfl_xor(s, mm, 64);
    float pa = 0.f;
    #pragma unroll
    for(int uu=0; uu<4; uu++){ int u = m*4+uu; pa += h_l[u]*Wa[u*R_ + r]; }
    #pragma unroll
    for(int mm=1;mm<64;mm<<=1) pa += __shfl_xor(pa, mm, 64);
    float al = sigm(tanh_f(pa + ba[r]));
    int q = r*256 + b;
    kt[q*64 + m]    = k;
    kt_bf[q*64 + m] = f2bf(k);
    aktT[(size_t)(r*64 + m)*256 + b] = f2bf(al*k);   // transposed, k(=b)-major
    if(m==0){ knorm[q] = sqrtf(s); alpha[q] = al; }
}

// ---------------- fused G-GEMM (MFMA) + scatter + tanh chain + Vt output ----------------
// grid 512 = N/64. Block 256 (4 waves). Wave w computes n-sub w (16 rows) x 64 m x all 4 r.
__global__ __launch_bounds__(256) void k_Gfused(const float* wrp, const unsigned short* aktT,
                                                const float* A, const float* kt, const float* alpha,
                                                const int* least, const int* lflag,
                                                unsigned short* Vt){
    __shared__ __align__(16) char wrl[16384];    // [64 n][256B row: (r*64+b*2) ^ ((n&7)<<4)] bf16
    __shared__ __align__(16) char aktl[16384];   // [64 m][256B row: (r*64+b*2) ^ ((m&7)<<4)] bf16
    __shared__ int least_l[256];
    int nb = blockIdx.x*64, t = threadIdx.x;
    int w = t>>6, lane = t&63;
    int r16 = lane&15, hq = lane>>4;
    for(int i=t;i<256;i+=256) least_l[i] = least[i];

    f32x4 acc[4][4];   // [r][msub]
    #pragma unroll
    for(int r=0;r<4;r++)
        #pragma unroll
        for(int ms=0;ms<4;ms++) acc[r][ms] = (f32x4){0.f,0.f,0.f,0.f};

    int sb = lane>>1, nh = (lane&1)*32;     // wr staging: lane -> (b, n-half)
    for(int kt8=0; kt8<8; kt8++){
        int b0 = kt8*32;
        __syncthreads();
        // ---- stage wr slice r=w: [32b][64n] -> bf16 transposed into wrl ----
        const float4* src = (const float4*)(wrp + ((size_t)w*B_ + b0 + sb)*N_ + nb + nh);
        float4 f[8];
        #pragma unroll
        for(int i=0;i<8;i++) f[i] = src[i];
        // ---- stage akt slice r=w: aktT[r][m][b0..b0+31] ----
        const uint4* ap = (const uint4*)(aktT + ((size_t)(w*64 + lane))*256 + b0);
        uint4 av[4];
        #pragma unroll
        for(int c=0;c<4;c++) av[c] = ap[c];
        #pragma unroll
        for(int i=0;i<8;i++){
            float vv[4] = {f[i].x, f[i].y, f[i].z, f[i].w};
            #pragma unroll
            for(int c=0;c<4;c++){
                int n = nh + i*4 + c;
                *(unsigned short*)(wrl + n*256 + ((w*64 + sb*2) ^ ((n&7)<<4))) = f2bf(vv[c]);
            }
        }
        #pragma unroll
        for(int c=0;c<4;c++)
            *(uint4*)(aktl + lane*256 + ((w*64 + c*16) ^ ((lane&7)<<4))) = av[c];
        __syncthreads();
        // ---- MFMA: D[n][m] += wr^T . akt ----
        #pragma unroll
        for(int r=0;r<4;r++){
            int n = w*16 + r16;
            short8v af = *(const short8v*)(wrl + n*256 + ((r*64 + hq*16) ^ ((n&7)<<4)));
            #pragma unroll
            for(int ms=0;ms<4;ms++){
                int m = ms*16 + r16;
                short8v bf = *(const short8v*)(aktl + m*256 + ((r*64 + hq*16) ^ ((m&7)<<4)));
                acc[r][ms] = __builtin_amdgcn_mfma_f32_16x16x32_bf16(af, bf, acc[r][ms], 0, 0, 0);
            }
        }
    }
    __syncthreads();   // frag reads done; reuse wrl as Vt-transpose tile [64m][128B]
    #pragma unroll
    for(int j=0;j<4;j++){
        int nl = w*16 + hq*4 + j, gn = nb + nl;
        int fl = lflag[gn];
        float er = fl ? 0.f : 1.f;
        float sadd[4][4];
        #pragma unroll
        for(int r=0;r<4;r++){ sadd[r][0]=0.f; sadd[r][1]=0.f; sadd[r][2]=0.f; sadd[r][3]=0.f; }
        if(fl){
            for(int b=0;b<256;b++){
                if(least_l[b]==gn){
                    #pragma unroll
                    for(int r=0;r<4;r++){
                        float am = 1.f - alpha[r*256+b];
                        const float* kp = kt + ((size_t)(r*256+b))*64 + r16;
                        #pragma unroll
                        for(int ms=0;ms<4;ms++) sadd[r][ms] += am * kp[ms*16];
                    }
                }
            }
        }
        #pragma unroll
        for(int ms=0;ms<4;ms++){
            int m = ms*16 + r16;
            float v = A[(size_t)gn*64 + m] * er;
            #pragma unroll
            for(int r=0;r<4;r++) v = tanh_f(v + acc[r][ms][j] + sadd[r][ms]);
            *(unsigned short*)(wrl + m*128 + ((nl*2) ^ ((m&7)<<4))) = f2bf(v);
        }
    }
    __syncthreads();
    int m = t>>2, cq = t&3;
    #pragma unroll
    for(int hh=0;hh<2;hh++){
        uint4 v = *(const uint4*)(wrl + m*128 + ((cq*32 + hh*16) ^ ((m&7)<<4)));
        *(uint4*)(Vt + (size_t)m*N_ + nb + cq*16 + hh*8) = v;
    }
}

// ---------------- fused attention: scores (MFMA) -> LDS P (bf16) -> PV (MFMA) ----------------
// grid: 1024 blocks = 64 n-parts x 16 q-tiles; block 256 = 4 waves, wave w owns 16 q rows.
__global__ __launch_bounds__(256) void k_attn(const unsigned short* kt_bf, const unsigned short* A_bf,
                                              const unsigned short* Vt, const float* knorm,
                                              const float* anorm, float* part, float* l){
    __shared__ __align__(16) unsigned short Pl[64*256];   // [64 q][256 n], XOR-swizzled
    int nc = blockIdx.x >> 4, qt = blockIdx.x & 15;
    int qb = qt*64, nb = nc*512;
    int lane = threadIdx.x & 63, w = threadIdx.x >> 6;
    int r16 = lane & 15, hq = lane >> 4;
    const short8v* kp = (const short8v*)(kt_bf + (size_t)(qb + w*16 + r16)*64 + hq*8);
    short8v ka0 = kp[0], ka1 = kp[4];
    float kn[4];
    #pragma unroll
    for(int j=0;j<4;j++) kn[j] = knorm[qb + w*16 + hq*4 + j];
    f32x4 O[4];
    #pragma unroll
    for(int mt=0;mt<4;mt++) O[mt] = (f32x4){0.f,0.f,0.f,0.f};
    float lp[4] = {0.f,0.f,0.f,0.f};
    int g2 = (r16 >> 2) & 3;

    for(int c=0; c<2; c++){
        int n0c = nb + c*256;
        __syncthreads();
        // ---- scores phase ----
        for(int nt=0; nt<16; nt++){
            int ntb = n0c + nt*16;
            const short8v* bp = (const short8v*)(A_bf + (size_t)(ntb + r16)*64 + hq*8);
            f32x4 acc = (f32x4){0.f,0.f,0.f,0.f};
            acc = __builtin_amdgcn_mfma_f32_16x16x32_bf16(ka0, bp[0], acc, 0, 0, 0);
            acc = __builtin_amdgcn_mfma_f32_16x16x32_bf16(ka1, bp[4], acc, 0, 0, 0);
            float an = anorm[ntb + r16];
            unsigned um[4];
            #pragma unroll
            for(int j=0;j<4;j++){
                float p = __expf(__fdividef(acc[j], kn[j]*an + 1e-16f));
                lp[j] += p;
                um[j] = (unsigned)f2bf(p);
            }
            int nl = nt*16 + (r16 & ~1);
            #pragma unroll
            for(int j=0;j<4;j++){
                unsigned up = __shfl_xor((int)um[j], 1, 64);
                if((lane & 1) == 0){
                    unsigned word = um[j] | (up << 16);
                    int byteoff = (w*16 + hq*4 + j)*512 + ((nl ^ (hq<<4)) << 1);
                    *(unsigned*)((char*)Pl + byteoff) = word;
                }
            }
        }
        __syncthreads();
        // ---- PV phase ----
        #pragma unroll 2
        for(int ks=0; ks<8; ks++){
            short8v pa = *(const short8v*)((const char*)Pl +
                          ((w*16 + r16)*512 + (((ks*32 + hq*8) ^ (g2<<4)) << 1)));
            #pragma unroll
            for(int mt=0; mt<4; mt++){
                const short8v* vp = (const short8v*)(Vt + (size_t)(mt*16 + r16)*N_ + n0c + ks*32 + hq*8);
                O[mt] = __builtin_amdgcn_mfma_f32_16x16x32_bf16(pa, vp[0], O[mt], 0, 0, 0);
            }
        }
    }
    #pragma unroll
    for(int mt=0; mt<4; mt++)
        #pragma unroll
        for(int j=0;j<4;j++)
            part[((size_t)nc*Q_ + (qb + w*16 + hq*4 + j))*64 + mt*16 + r16] = O[mt][j];
    #pragma unroll
    for(int j=0;j<4;j++){
        #pragma unroll
        for(int m2=1;m2<16;m2<<=1) lp[j] += __shfl_xor(lp[j], m2, 64);
        if(r16 == 0) atomicAdd(l + qb + w*16 + hq*4 + j, lp[j]);
    }
}

// ---------------- final reduce over n-parts, normalize, write reads ----------------
__global__ __launch_bounds__(256) void k_reduce(const float* part, const float* l, float* out){
    int tg = blockIdx.x*256 + threadIdx.x;   // 65536 = Q_*64
    int q = tg >> 6, m = tg & 63;
    float s = 0.f;
    for(int cc=0;cc<NPART_;cc++) s += part[(size_t)cc*(Q_*64) + tg];
    float val = s / l[q];
    int r = q >> 8, b = q & 255;
    out[(size_t)b*512 + 256 + r*64 + m] = val;
}

extern "C" void kernel_launch(void* const* d_in, const int* in_sizes, int n_in,
                              void* d_out, int out_size, void* d_ws, size_t ws_size,
                              hipStream_t stream) {
    const float* x        = (const float*)d_in[0];
    const float* A        = (const float*)d_in[1];
    const float* wr_prev  = (const float*)d_in[2];
    const float* wu_prev  = (const float*)d_in[3];
    const float* read_prev= (const float*)d_in[4];
    const float* h        = (const float*)d_in[5];
    const float* c        = (const float*)d_in[6];
    const float* W        = (const float*)d_in[7];
    const float* Uw       = (const float*)d_in[8];
    const float* bvec     = (const float*)d_in[9];
    const float* Wk       = (const float*)d_in[10];
    const float* bk       = (const float*)d_in[11];
    const float* Wa       = (const float*)d_in[12];
    const float* ba       = (const float*)d_in[13];
    float* out = (float*)d_out;

    char* wsp = (char*)d_ws;
    float* gpart  = (float*)(wsp);                              // 16 MB
    float* part   = (float*)(wsp + 16777216);                   // 16 MB
    unsigned short* A_bf  = (unsigned short*)(wsp + 33554432);  // 4 MB
    unsigned short* Vt_bf = (unsigned short*)(wsp + 37748736);  // 4 MB
    unsigned short* aktT  = (unsigned short*)(wsp + 41943040);  // 128 KB
    float* kt     = (float*)(wsp + 42074112);                   // 256 KB
    unsigned short* kt_bf = (unsigned short*)(wsp + 42336256);  // 128 KB
    float* h_new  = (float*)(wsp + 42467328);                   // 256 KB
    float* alpha  = (float*)(wsp + 42729472);
    float* knorm  = (float*)(wsp + 42733568);
    float* anorm  = (float*)(wsp + 42737664);
    int*   lflag  = (int*)  (wsp + 42868736);
    float* l      = (float*)(wsp + 42999808);
    int*   least  = (int*)  (wsp + 43003904);

    k_zero     <<<128, 256, 0, stream>>>(lflag, l);
    k_anorm    <<<8192,256, 0, stream>>>(A, anorm, A_bf);
    k_argmin   <<<256, 256, 0, stream>>>(wu_prev, least, lflag);
    k_lstm_gemm<<<512, 256, 0, stream>>>(x, read_prev, h, W, Uw, gpart);
    k_lstm_act <<<256, 256, 0, stream>>>(gpart, bvec, c, h_new, out);
    k_kta      <<<1024, 64, 0, stream>>>(h_new, Wk, bk, Wa, ba, kt, kt_bf, aktT, alpha, knorm);
    k_Gfused   <<<512, 256, 0, stream>>>(wr_prev, aktT, A, kt, alpha, least, lflag, Vt_bf);
    k_attn     <<<1024,256, 0, stream>>>(kt_bf, A_bf, Vt_bf, knorm, anorm, part, l);
    k_reduce   <<<256, 256, 0, stream>>>(part, l, out);
}